// Round 7
// baseline (174.233 us; speedup 1.0000x reference)
//
#include <hip/hip_runtime.h>
#include <hip/hip_bf16.h>

// 3-kernel pipeline:
//   T: x [b][c][d][hw] fp32 -> xT [b][d][hw][c] bf16; weights -> fragmented bf16
//   F: fused QKV + per-(b,hw) attention, 48KB LDS, 3 blocks/CU.
//      att -> [b][d][hw][s] bf16.
//   C: out-projection + bias + residual, operand-swapped MFMA so acc f32x4 ==
//      out float4 (r spans hw): direct register->global stores, no LDS stage.
//      32KB slab -> 4 blocks/CU.
// Fallback: round-1 fused kernel if workspace too small.

typedef __bf16 bf16_t;
typedef bf16_t bf16x8 __attribute__((ext_vector_type(8)));
typedef bf16_t bf16x4 __attribute__((ext_vector_type(4)));
typedef float  f32x4  __attribute__((ext_vector_type(4)));

#define NB   8
#define NC   256
#define ND   64
#define NHW  256
#define NS   128

#define MFMA16 __builtin_amdgcn_mfma_f32_16x16x32_bf16

__device__ __forceinline__ int swz(int row, int col) {
  return col ^ ((row & 7) << 3);
}

__device__ __forceinline__ bf16x8 pack8(float4 a, float4 b) {
  bf16x8 r;
  r[0] = (bf16_t)a.x; r[1] = (bf16_t)a.y; r[2] = (bf16_t)a.z; r[3] = (bf16_t)a.w;
  r[4] = (bf16_t)b.x; r[5] = (bf16_t)b.y; r[6] = (bf16_t)b.z; r[7] = (bf16_t)b.w;
  return r;
}

__device__ __forceinline__ bf16x8 ldg_w8(const float* p) {
  float4 a = *(const float4*)p;
  float4 b = *(const float4*)(p + 4);
  return pack8(a, b);
}

// ================= Kernel T: transpose x -> xT bf16; fragment weights ========
// grid 8224: [0,8192): 64c x 64hw tile per (b,d); [8192,8224): weights
__global__ __launch_bounds__(256) void transpose_x_w(
    const float* __restrict__ x,
    const float* __restrict__ wk, const float* __restrict__ wq,
    const float* __restrict__ wv, const float* __restrict__ wo,
    bf16_t* __restrict__ xT, bf16_t* __restrict__ wsW) {
  __shared__ bf16_t tile[64 * 72];   // [hw][c] pad to 72
  const int bid = blockIdx.x;
  if (bid >= 8192) {
    const int wid = bid - 8192;
    const int mat = wid >> 3, sub = wid & 7;
    const int t = threadIdx.x;
    if (mat < 3) {
      // wk/wq/wv [128 s][256 c] -> frag [32 cg][128 s][8]
      const float* src = (mat == 0) ? wk : (mat == 1) ? wq : wv;
      bf16_t* dst = wsW + mat * 32768;
      int s = sub * 16 + (t >> 4), c0 = (t & 15) * 16;
      const float* p = src + s * NC + c0;
      float4 a0 = *(const float4*)p, a1 = *(const float4*)(p + 4);
      float4 a2 = *(const float4*)(p + 8), a3 = *(const float4*)(p + 12);
      *(bf16x8*)(dst + (c0 >> 3) * 1024 + s * 8)       = pack8(a0, a1);
      *(bf16x8*)(dst + ((c0 >> 3) + 1) * 1024 + s * 8) = pack8(a2, a3);
    } else {
      // wo [256 c][128 s] -> frag [16 sg][256 c][8]
      bf16_t* dst = wsW + 98304;
      int c = sub * 32 + (t >> 3), sc0 = (t & 7) * 16;
      const float* p = wo + c * NS + sc0;
      float4 a0 = *(const float4*)p, a1 = *(const float4*)(p + 4);
      float4 a2 = *(const float4*)(p + 8), a3 = *(const float4*)(p + 12);
      *(bf16x8*)(dst + (sc0 >> 3) * 2048 + c * 8)       = pack8(a0, a1);
      *(bf16x8*)(dst + ((sc0 >> 3) + 1) * 2048 + c * 8) = pack8(a2, a3);
    }
    return;
  }
  const int ct = bid & 3, hwt = (bid >> 2) & 3;
  const int d = (bid >> 4) & 63, b = bid >> 10;
  const int c0 = ct * 64, hw0 = hwt * 64;
  const int t = threadIdx.x;
  const int hwq = t & 15, chi = t >> 4;

  #pragma unroll
  for (int q = 0; q < 4; ++q) {
    int c = q * 16 + chi;
    float4 v4 = *(const float4*)(x + ((size_t)((b * NC + c0 + c) * ND + d)) * NHW + hw0 + hwq * 4);
    tile[(hwq * 4 + 0) * 72 + c] = (bf16_t)v4.x;
    tile[(hwq * 4 + 1) * 72 + c] = (bf16_t)v4.y;
    tile[(hwq * 4 + 2) * 72 + c] = (bf16_t)v4.z;
    tile[(hwq * 4 + 3) * 72 + c] = (bf16_t)v4.w;
  }
  __syncthreads();
  #pragma unroll
  for (int i = 0; i < 2; ++i) {
    int idx = t + 256 * i;
    int hw = idx >> 3, q = idx & 7;
    bf16x8 v8 = *(const bf16x8*)&tile[hw * 72 + q * 8];
    *(bf16x8*)(xT + ((size_t)((b * ND + d) * NHW + hw0 + hw)) * NC + c0 + q * 8) = v8;
  }
}

// ================= Kernel F: fused QKV + attention (48KB LDS) =================
// grid 2048 = (hw,b); 256 threads (4 waves); 3 blocks/CU.
__global__ __launch_bounds__(256, 3) void qkv_attn3(
    const bf16_t* __restrict__ xT, const bf16_t* __restrict__ wsW,
    const float* __restrict__ bk, const float* __restrict__ bq,
    const float* __restrict__ bv, bf16_t* __restrict__ att) {
  __shared__ bf16_t lds[24576];          // 48 KB
  bf16_t* kT   = lds;                    // [d][s] swz (8192 els)
  bf16_t* qT   = lds + 8192;             // [d][s] swz
  bf16_t* vS   = lds + 16384;            // [s][d] swz
  bf16_t* xTl  = lds;                    // [d][128c] swz (slice; dead pre-epilogue)
  bf16_t* aT   = lds;                    // [j][i] swz (4096 els; post-QK^T)
  bf16_t* attT = lds + 8192;             // [d][s] swz (post-QK^T)

  const int gid = blockIdx.x;
  const int b = gid & 7, hw = gid >> 3;
  const int t = threadIdx.x, w = t >> 6, lane = t & 63;
  const int l16 = lane & 15, q4 = lane >> 4;

  const int mat = w >> 1;
  const int sb = (w & 1) * 64;
  const bf16_t* wm = mat ? (wsW + 32768) : wsW;    // wq : wk frag
  const bf16_t* wvF = wsW + 65536;
  const float* bm = mat ? bq : bk;
  bf16_t* dstKQ = mat ? qT : kT;
  const int sbv = w * 32;

  f32x4 acc[4][4] = {};     // K-or-Q accumulator (row=s, col=d)
  f32x4 accv[4][2] = {};    // V accumulator (row=d, col=s)

  for (int cc = 0; cc < 2; ++cc) {
    __syncthreads();
    #pragma unroll
    for (int jj = 0; jj < 4; ++jj) {
      int id = jj * 256 + t;
      int d = id >> 4, cg = (id & 15) * 8;
      bf16x8 v8 = *(const bf16x8*)(xT + ((size_t)((b * ND + d) * NHW + hw)) * NC + cc * 128 + cg);
      *(bf16x8*)&xTl[d * 128 + swz(d, cg)] = v8;
    }
    __syncthreads();
    #pragma unroll
    for (int ks = 0; ks < 4; ++ks) {
      const int kb = ks * 32 + q4 * 8;
      const int kgf = ((cc * 128 + kb) >> 3) * 1024;
      bf16x8 xfr[4], afk[4], bfv[2];
      #pragma unroll
      for (int i = 0; i < 4; ++i) {
        int row = i * 16 + l16;
        xfr[i] = *(const bf16x8*)&xTl[row * 128 + swz(row, kb)];
        int s = sb + i * 16 + l16;
        afk[i] = *(const bf16x8*)(wm + kgf + s * 8);
      }
      #pragma unroll
      for (int i = 0; i < 2; ++i) {
        int s = sbv + i * 16 + l16;
        bfv[i] = *(const bf16x8*)(wvF + kgf + s * 8);
      }
      #pragma unroll
      for (int nt = 0; nt < 4; ++nt)
        #pragma unroll
        for (int mt = 0; mt < 4; ++mt)
          acc[mt][nt] = MFMA16(afk[mt], xfr[nt], acc[mt][nt], 0, 0, 0);
      #pragma unroll
      for (int nt = 0; nt < 2; ++nt)
        #pragma unroll
        for (int mt = 0; mt < 4; ++mt)
          accv[mt][nt] = MFMA16(xfr[mt], bfv[nt], accv[mt][nt], 0, 0, 0);
    }
  }
  __syncthreads();   // xTl dead; epilogue overwrites its region (kT)

  // ---- epilogue: K/Q -> kT/qT [d][s]; V -> vS [s][d] ----
  #pragma unroll
  for (int mt = 0; mt < 4; ++mt) {
    int s0 = sb + mt * 16 + q4 * 4;
    float4 b4 = *(const float4*)(bm + s0);
    #pragma unroll
    for (int nt = 0; nt < 4; ++nt) {
      int d = nt * 16 + l16;
      bf16x4 pk;
      pk[0] = (bf16_t)(acc[mt][nt][0] + b4.x);
      pk[1] = (bf16_t)(acc[mt][nt][1] + b4.y);
      pk[2] = (bf16_t)(acc[mt][nt][2] + b4.z);
      pk[3] = (bf16_t)(acc[mt][nt][3] + b4.w);
      *(bf16x4*)&dstKQ[d * NS + swz(d, s0)] = pk;
    }
  }
  #pragma unroll
  for (int nt = 0; nt < 2; ++nt) {
    int s = sbv + nt * 16 + l16;
    float bvs = bv[s];
    #pragma unroll
    for (int mt = 0; mt < 4; ++mt) {
      int d0 = mt * 16 + q4 * 4;
      bf16x4 pv;
      pv[0] = (bf16_t)(accv[mt][nt][0] + bvs);
      pv[1] = (bf16_t)(accv[mt][nt][1] + bvs);
      pv[2] = (bf16_t)(accv[mt][nt][2] + bvs);
      pv[3] = (bf16_t)(accv[mt][nt][3] + bvs);
      *(bf16x4*)&vS[s * ND + (d0 ^ ((s & 7) << 3))] = pv;
    }
  }
  __syncthreads();

  // ---- scores + softmax ----
  float ps[16];
  {
    f32x4 sacc[4] = {};
    for (int ks = 0; ks < 4; ++ks) {
      const int kb = ks * 32 + q4 * 8;
      int jrow = w * 16 + l16;
      bf16x8 bfr = *(const bf16x8*)&qT[jrow * NS + swz(jrow, kb)];
      #pragma unroll
      for (int it = 0; it < 4; ++it) {
        int irow = it * 16 + l16;
        bf16x8 afr = *(const bf16x8*)&kT[irow * NS + swz(irow, kb)];
        sacc[it] = MFMA16(afr, bfr, sacc[it], 0, 0, 0);
      }
    }
    const float scale = 0.088388347648318447f;  // 1/sqrt(128)
    float mx = -1e30f;
    #pragma unroll
    for (int it = 0; it < 4; ++it)
      #pragma unroll
      for (int r = 0; r < 4; ++r) {
        float vv = sacc[it][r] * scale;
        ps[it * 4 + r] = vv;
        mx = fmaxf(mx, vv);
      }
    mx = fmaxf(mx, __shfl_xor(mx, 16));
    mx = fmaxf(mx, __shfl_xor(mx, 32));
    float sum = 0.f;
    #pragma unroll
    for (int i = 0; i < 16; ++i) { ps[i] = __expf(ps[i] - mx); sum += ps[i]; }
    sum += __shfl_xor(sum, 16);
    sum += __shfl_xor(sum, 32);
    float inv = 1.f / sum;
    #pragma unroll
    for (int i = 0; i < 16; ++i) ps[i] *= inv;
  }
  __syncthreads();

  {
    int j = w * 16 + l16;
    #pragma unroll
    for (int it = 0; it < 4; ++it) {
      bf16x4 pk;
      #pragma unroll
      for (int r = 0; r < 4; ++r) pk[r] = (bf16_t)ps[it * 4 + r];
      *(bf16x4*)&aT[j * ND + ((it * 16 + q4 * 4) ^ ((j & 7) << 3))] = pk;
    }
  }
  __syncthreads();

  // ---- PV -> attT[j][s] ----
  {
    const int sbp = w * 32;
    f32x4 pacc[2][4] = {};
    #pragma unroll
    for (int ki = 0; ki < 2; ++ki) {
      const int kb = ki * 32 + q4 * 8;
      bf16x8 afr[2];
      #pragma unroll
      for (int mt = 0; mt < 2; ++mt) {
        int srow = sbp + mt * 16 + l16;
        afr[mt] = *(const bf16x8*)&vS[srow * ND + (kb ^ ((srow & 7) << 3))];
      }
      #pragma unroll
      for (int nt = 0; nt < 4; ++nt) {
        int jrow = nt * 16 + l16;
        bf16x8 bfr = *(const bf16x8*)&aT[jrow * ND + (kb ^ ((jrow & 7) << 3))];
        #pragma unroll
        for (int mt = 0; mt < 2; ++mt)
          pacc[mt][nt] = MFMA16(afr[mt], bfr, pacc[mt][nt], 0, 0, 0);
      }
    }
    #pragma unroll
    for (int nt = 0; nt < 4; ++nt) {
      int j = nt * 16 + l16;
      #pragma unroll
      for (int mt = 0; mt < 2; ++mt) {
        bf16x4 pk;
        #pragma unroll
        for (int r = 0; r < 4; ++r) pk[r] = (bf16_t)pacc[mt][nt][r];
        *(bf16x4*)&attT[j * NS + swz(j, sbp + mt * 16 + q4 * 4)] = pk;
      }
    }
  }
  __syncthreads();

  #pragma unroll
  for (int jj = 0; jj < 4; ++jj) {
    int f = jj * 2048 + t * 8;
    int d = f >> 7, s0 = f & 127;
    bf16x8 v8 = *(const bf16x8*)&attT[d * NS + (s0 ^ ((d & 7) << 3))];
    *(bf16x8*)(att + ((size_t)((b * ND + d) * NHW + hw)) * NS + s0) = v8;
  }
}

// ================= Kernel C: out projection + residual (operand-swapped) =====
// grid 2048 = ht(8: 32hw) * dcq(16: 4d) * ch(2: 128c) * b(8)
// A = att slab rows (m = d*32+hw), B = woF (n = c): acc f32x4 r spans hw ->
// direct float4 stores. 32KB LDS -> 4 blocks/CU.
__global__ __launch_bounds__(256, 4) void out_proj2(
    const bf16_t* __restrict__ att_ws,
    const bf16_t* __restrict__ woF, const float* __restrict__ bo,
    const float* __restrict__ x, float* __restrict__ out) {
  __shared__ bf16_t slab[128 * 128];  // rows = d4*32+hw, slot16-XOR by hw&7
  const int bid = blockIdx.x;
  const int ht = bid & 7, dcq = (bid >> 3) & 15, ch = (bid >> 7) & 1, b = bid >> 8;
  const int t = threadIdx.x, w = t >> 6, lane = t & 63;
  const int l16 = lane & 15, q4 = lane >> 4;

  // stage att -> slab (dense 1024B wave reads)
  {
    const int j = t & 15;            // s-chunk
    const int r0 = t >> 4;           // row within pass
    #pragma unroll
    for (int pp = 0; pp < 8; ++pp) {
      int row = pp * 16 + r0;
      int d = row >> 5, hw = row & 31;
      bf16x8 v8 = *(const bf16x8*)(att_ws +
          ((size_t)((b * ND + dcq * 4 + d) * NHW + ht * 32 + hw)) * NS + j * 8);
      *(bf16x8*)&slab[row * NS + ((j ^ (hw & 7)) << 3)] = v8;
    }
  }
  __syncthreads();

  f32x4 acc[2][8] = {};
  #pragma unroll
  for (int kq = 0; kq < 4; ++kq) {
    bf16x8 af[2];
    #pragma unroll
    for (int mt = 0; mt < 2; ++mt) {
      int row = (w * 2 + mt) * 16 + l16;
      af[mt] = *(const bf16x8*)&slab[row * NS + (((kq * 4 + q4) ^ (row & 7)) << 3)];
    }
    #pragma unroll
    for (int nt = 0; nt < 8; ++nt) {
      int c = ch * 128 + nt * 16 + l16;
      bf16x8 bfr = *(const bf16x8*)(woF + (kq * 4 + q4) * 2048 + c * 8);
      #pragma unroll
      for (int mt = 0; mt < 2; ++mt)
        acc[mt][nt] = MFMA16(af[mt], bfr, acc[mt][nt], 0, 0, 0);
    }
  }

  // epilogue: C row = q4*4+r spans hw -> direct float4 I/O
  #pragma unroll
  for (int mt = 0; mt < 2; ++mt) {
    int mrow = w * 2 + mt;                      // tile in [0,8)
    int d = dcq * 4 + (mrow >> 1);
    int hw0 = ht * 32 + (mrow & 1) * 16 + q4 * 4;
    #pragma unroll
    for (int nt = 0; nt < 8; ++nt) {
      int c = ch * 128 + nt * 16 + l16;
      size_t gi = ((size_t)(b * NC + c) * ND + d) * NHW + hw0;
      float4 xv = *(const float4*)(x + gi);
      float bias = bo[c];
      float4 o;
      o.x = acc[mt][nt][0] + bias + xv.x;
      o.y = acc[mt][nt][1] + bias + xv.y;
      o.z = acc[mt][nt][2] + bias + xv.z;
      o.w = acc[mt][nt][3] + bias + xv.w;
      *(float4*)(out + gi) = o;
    }
  }
}

// ================= Fallback: round-1 fused kernel =================
struct SMemF {
  union {
    bf16_t xT[ND * NC];
    struct { bf16_t aT[ND * ND]; bf16_t attT[ND * NS]; } p2;
  } u;
  bf16_t kT[ND * NS];
  bf16_t qT[ND * NS];
  bf16_t vS[NS * ND];
};

__global__ __launch_bounds__(256) void attn_fused(
    const float* __restrict__ x,
    const float* __restrict__ wk, const float* __restrict__ bk,
    const float* __restrict__ wq, const float* __restrict__ bq,
    const float* __restrict__ wv, const float* __restrict__ bv,
    const float* __restrict__ wo, const float* __restrict__ bo,
    float* __restrict__ out) {
  __shared__ SMemF sm;
  const int gid = blockIdx.x;
  const int b = gid & 7;
  const int hw = gid >> 3;
  const int t = threadIdx.x;
  const int w = t >> 6;
  const int lane = t & 63;
  const int l16 = lane & 15;
  const int q4 = lane >> 4;
  const float* xb = x + (size_t)b * NC * ND * NHW + hw;
  {
    const int d = t & 63;
    const int cb = (t >> 6) * 64;
    for (int jj = 0; jj < 8; ++jj) {
      bf16x8 pk;
      #pragma unroll
      for (int e = 0; e < 8; ++e) {
        int c = cb + jj * 8 + e;
        pk[e] = (bf16_t)xb[(size_t)(c * ND + d) * NHW];
      }
      *(bf16x8*)&sm.u.xT[d * NC + swz(d, cb + jj * 8)] = pk;
    }
  }
  __syncthreads();
  {
    const int mat = w >> 1;
    const int sb = (w & 1) * 64;
    const float* wm = mat ? wq : wk;
    const float* bm = mat ? bq : bk;
    bf16_t* dst = mat ? sm.qT : sm.kT;
    f32x4 acc[4][4] = {};
    for (int ks = 0; ks < 8; ++ks) {
      const int kb = ks * 32 + q4 * 8;
      bf16x8 afr[4];
      #pragma unroll
      for (int mt = 0; mt < 4; ++mt) {
        int row = mt * 16 + l16;
        afr[mt] = *(const bf16x8*)&sm.u.xT[row * NC + swz(row, kb)];
      }
      #pragma unroll
      for (int st = 0; st < 4; ++st) {
        int s = sb + st * 16 + l16;
        bf16x8 bfr = ldg_w8(wm + s * NC + kb);
        #pragma unroll
        for (int mt = 0; mt < 4; ++mt)
          acc[mt][st] = MFMA16(afr[mt], bfr, acc[mt][st], 0, 0, 0);
      }
    }
    #pragma unroll
    for (int st = 0; st < 4; ++st) {
      int s = sb + st * 16 + l16;
      float bias = bm[s];
      #pragma unroll
      for (int mt = 0; mt < 4; ++mt) {
        #pragma unroll
        for (int r = 0; r < 4; ++r) {
          int d = mt * 16 + q4 * 4 + r;
          dst[d * NS + swz(d, s)] = (bf16_t)(acc[mt][st][r] + bias);
        }
      }
    }
  }
  {
    const int sb = w * 32;
    f32x4 acc[2][4] = {};
    for (int ks = 0; ks < 8; ++ks) {
      const int kb = ks * 32 + q4 * 8;
      bf16x8 afr[2];
      #pragma unroll
      for (int mt = 0; mt < 2; ++mt)
        afr[mt] = ldg_w8(wv + (sb + mt * 16 + l16) * NC + kb);
      #pragma unroll
      for (int nt = 0; nt < 4; ++nt) {
        int row = nt * 16 + l16;
        bf16x8 bfr = *(const bf16x8*)&sm.u.xT[row * NC + swz(row, kb)];
        #pragma unroll
        for (int mt = 0; mt < 2; ++mt)
          acc[mt][nt] = MFMA16(afr[mt], bfr, acc[mt][nt], 0, 0, 0);
      }
    }
    #pragma unroll
    for (int mt = 0; mt < 2; ++mt) {
      #pragma unroll
      for (int r = 0; r < 4; ++r) {
        int s = sb + mt * 16 + q4 * 4 + r;
        float bias = bv[s];
        #pragma unroll
        for (int nt = 0; nt < 4; ++nt) {
          int d = nt * 16 + l16;
          sm.vS[s * ND + swz(s, d)] = (bf16_t)(acc[mt][nt][r] + bias);
        }
      }
    }
  }
  __syncthreads();
  {
    f32x4 sacc[4] = {};
    for (int ks = 0; ks < 4; ++ks) {
      const int kb = ks * 32 + q4 * 8;
      int jrow = w * 16 + l16;
      bf16x8 bfr = *(const bf16x8*)&sm.qT[jrow * NS + swz(jrow, kb)];
      #pragma unroll
      for (int it = 0; it < 4; ++it) {
        int irow = it * 16 + l16;
        bf16x8 afr = *(const bf16x8*)&sm.kT[irow * NS + swz(irow, kb)];
        sacc[it] = MFMA16(afr, bfr, sacc[it], 0, 0, 0);
      }
    }
    const float scale = 0.088388347648318447f;
    float ps[16];
    float mx = -1e30f;
    #pragma unroll
    for (int it = 0; it < 4; ++it) {
      #pragma unroll
      for (int r = 0; r < 4; ++r) {
        float vv = sacc[it][r] * scale;
        ps[it * 4 + r] = vv;
        mx = fmaxf(mx, vv);
      }
    }
    mx = fmaxf(mx, __shfl_xor(mx, 16));
    mx = fmaxf(mx, __shfl_xor(mx, 32));
    float sum = 0.f;
    #pragma unroll
    for (int i = 0; i < 16; ++i) { ps[i] = __expf(ps[i] - mx); sum += ps[i]; }
    sum += __shfl_xor(sum, 16);
    sum += __shfl_xor(sum, 32);
    float inv = 1.f / sum;
    int j = w * 16 + l16;
    #pragma unroll
    for (int it = 0; it < 4; ++it) {
      bf16x4 pk;
      #pragma unroll
      for (int r = 0; r < 4; ++r) pk[r] = (bf16_t)(ps[it * 4 + r] * inv);
      *(bf16x4*)&sm.u.p2.aT[j * ND + swz(j, it * 16 + q4 * 4)] = pk;
    }
  }
  __syncthreads();
  {
    const int sb = w * 32;
    f32x4 acc[2][4] = {};
    #pragma unroll
    for (int ki = 0; ki < 2; ++ki) {
      const int kb = ki * 32 + q4 * 8;
      bf16x8 afr[2];
      #pragma unroll
      for (int mt = 0; mt < 2; ++mt) {
        int srow = sb + mt * 16 + l16;
        afr[mt] = *(const bf16x8*)&sm.vS[srow * ND + swz(srow, kb)];
      }
      #pragma unroll
      for (int nt = 0; nt < 4; ++nt) {
        int jrow = nt * 16 + l16;
        bf16x8 bfr = *(const bf16x8*)&sm.u.p2.aT[jrow * ND + swz(jrow, kb)];
        #pragma unroll
        for (int mt = 0; mt < 2; ++mt)
          acc[mt][nt] = MFMA16(afr[mt], bfr, acc[mt][nt], 0, 0, 0);
      }
    }
    #pragma unroll
    for (int nt = 0; nt < 4; ++nt) {
      int j = nt * 16 + l16;
      #pragma unroll
      for (int mt = 0; mt < 2; ++mt) {
        bf16x4 pk;
        #pragma unroll
        for (int r = 0; r < 4; ++r) pk[r] = (bf16_t)acc[mt][nt][r];
        *(bf16x4*)&sm.u.p2.attT[j * NS + swz(j, sb + mt * 16 + q4 * 4)] = pk;
      }
    }
  }
  __syncthreads();
  {
    const int cb = w * 64;
    f32x4 acc[4][4] = {};
    for (int ks = 0; ks < 4; ++ks) {
      const int kb = ks * 32 + q4 * 8;
      bf16x8 afr[4];
      #pragma unroll
      for (int mt = 0; mt < 4; ++mt)
        afr[mt] = ldg_w8(wo + (cb + mt * 16 + l16) * NS + kb);
      #pragma unroll
      for (int nt = 0; nt < 4; ++nt) {
        int jrow = nt * 16 + l16;
        bf16x8 bfr = *(const bf16x8*)&sm.u.p2.attT[jrow * NS + swz(jrow, kb)];
        #pragma unroll
        for (int mt = 0; mt < 4; ++mt)
          acc[mt][nt] = MFMA16(afr[mt], bfr, acc[mt][nt], 0, 0, 0);
      }
    }
    #pragma unroll
    for (int mt = 0; mt < 4; ++mt) {
      #pragma unroll
      for (int r = 0; r < 4; ++r) {
        int c = cb + mt * 16 + q4 * 4 + r;
        float bias = bo[c];
        #pragma unroll
        for (int nt = 0; nt < 4; ++nt) {
          int d = nt * 16 + l16;
          size_t gi = (size_t)(((b * NC + c) * ND + d) * NHW + hw);
          out[gi] = acc[mt][nt][r] + bias + x[gi];
        }
      }
    }
  }
}

extern "C" void kernel_launch(void* const* d_in, const int* in_sizes, int n_in,
                              void* d_out, int out_size, void* d_ws, size_t ws_size,
                              hipStream_t stream) {
  const float* x  = (const float*)d_in[0];
  const float* wk = (const float*)d_in[1];
  const float* bk = (const float*)d_in[2];
  const float* wq = (const float*)d_in[3];
  const float* bq = (const float*)d_in[4];
  const float* wv = (const float*)d_in[5];
  const float* bv = (const float*)d_in[6];
  const float* wo = (const float*)d_in[7];
  const float* bo = (const float*)d_in[8];
  float* out = (float*)d_out;

  // ws: [weights bf16 131072 el | xT 33554432 el | att 16777216 el]
  const size_t need = (size_t)(131072 + 33554432 + 16777216) * 2;
  if (ws_size >= need) {
    bf16_t* wsW = (bf16_t*)d_ws;
    bf16_t* xT  = wsW + 131072;
    bf16_t* att = xT + 33554432;
    transpose_x_w<<<dim3(8224), dim3(256), 0, stream>>>(x, wk, wq, wv, wo, xT, wsW);
    qkv_attn3<<<dim3(2048), dim3(256), 0, stream>>>(xT, wsW, bk, bq, bv, att);
    out_proj2<<<dim3(2048), dim3(256), 0, stream>>>(att, wsW + 98304, bo, x, out);
  } else {
    attn_fused<<<dim3(2048), dim3(256), 0, stream>>>(x, wk, bk, wq, bq, wv, bv, wo, bo, out);
  }
}

// Round 8
// 134.490 us; speedup vs baseline: 1.2955x; 1.2955x over previous
//
#include <hip/hip_runtime.h>
#include <hip/hip_bf16.h>

// 3-kernel pipeline:
//   T: x [b][c][d][hw] fp32 -> xT [b][d][hw][c] bf16; weights -> fragmented bf16
//   F: fused QKV + per-(b,hw) attention, 48KB LDS, 3 blocks/CU.
//      att -> [b][d][hw][s] bf16.
//   C: out-projection + bias + residual. 4d x 32hw x 128c block, 33.8KB LDS
//      (slab/stage union) -> 4 blocks/CU; staged fp32 epilogue with dense
//      128B-line float4 stores (round-6 write pattern, round-7 occupancy).
// Fallback: round-1 fused kernel if workspace too small.

typedef __bf16 bf16_t;
typedef bf16_t bf16x8 __attribute__((ext_vector_type(8)));
typedef bf16_t bf16x4 __attribute__((ext_vector_type(4)));
typedef float  f32x4  __attribute__((ext_vector_type(4)));

#define NB   8
#define NC   256
#define ND   64
#define NHW  256
#define NS   128

#define MFMA16 __builtin_amdgcn_mfma_f32_16x16x32_bf16

__device__ __forceinline__ int swz(int row, int col) {
  return col ^ ((row & 7) << 3);
}

__device__ __forceinline__ bf16x8 pack8(float4 a, float4 b) {
  bf16x8 r;
  r[0] = (bf16_t)a.x; r[1] = (bf16_t)a.y; r[2] = (bf16_t)a.z; r[3] = (bf16_t)a.w;
  r[4] = (bf16_t)b.x; r[5] = (bf16_t)b.y; r[6] = (bf16_t)b.z; r[7] = (bf16_t)b.w;
  return r;
}

__device__ __forceinline__ bf16x8 ldg_w8(const float* p) {
  float4 a = *(const float4*)p;
  float4 b = *(const float4*)(p + 4);
  return pack8(a, b);
}

// ================= Kernel T: transpose x -> xT bf16; fragment weights ========
// grid 8224: [0,8192): 64c x 64hw tile per (b,d); [8192,8224): weights
__global__ __launch_bounds__(256) void transpose_x_w(
    const float* __restrict__ x,
    const float* __restrict__ wk, const float* __restrict__ wq,
    const float* __restrict__ wv, const float* __restrict__ wo,
    bf16_t* __restrict__ xT, bf16_t* __restrict__ wsW) {
  __shared__ bf16_t tile[64 * 72];   // [hw][c] pad to 72
  const int bid = blockIdx.x;
  if (bid >= 8192) {
    const int wid = bid - 8192;
    const int mat = wid >> 3, sub = wid & 7;
    const int t = threadIdx.x;
    if (mat < 3) {
      // wk/wq/wv [128 s][256 c] -> frag [32 cg][128 s][8]
      const float* src = (mat == 0) ? wk : (mat == 1) ? wq : wv;
      bf16_t* dst = wsW + mat * 32768;
      int s = sub * 16 + (t >> 4), c0 = (t & 15) * 16;
      const float* p = src + s * NC + c0;
      float4 a0 = *(const float4*)p, a1 = *(const float4*)(p + 4);
      float4 a2 = *(const float4*)(p + 8), a3 = *(const float4*)(p + 12);
      *(bf16x8*)(dst + (c0 >> 3) * 1024 + s * 8)       = pack8(a0, a1);
      *(bf16x8*)(dst + ((c0 >> 3) + 1) * 1024 + s * 8) = pack8(a2, a3);
    } else {
      // wo [256 c][128 s] -> frag [16 sg][256 c][8]
      bf16_t* dst = wsW + 98304;
      int c = sub * 32 + (t >> 3), sc0 = (t & 7) * 16;
      const float* p = wo + c * NS + sc0;
      float4 a0 = *(const float4*)p, a1 = *(const float4*)(p + 4);
      float4 a2 = *(const float4*)(p + 8), a3 = *(const float4*)(p + 12);
      *(bf16x8*)(dst + (sc0 >> 3) * 2048 + c * 8)       = pack8(a0, a1);
      *(bf16x8*)(dst + ((sc0 >> 3) + 1) * 2048 + c * 8) = pack8(a2, a3);
    }
    return;
  }
  const int ct = bid & 3, hwt = (bid >> 2) & 3;
  const int d = (bid >> 4) & 63, b = bid >> 10;
  const int c0 = ct * 64, hw0 = hwt * 64;
  const int t = threadIdx.x;
  const int hwq = t & 15, chi = t >> 4;

  #pragma unroll
  for (int q = 0; q < 4; ++q) {
    int c = q * 16 + chi;
    float4 v4 = *(const float4*)(x + ((size_t)((b * NC + c0 + c) * ND + d)) * NHW + hw0 + hwq * 4);
    tile[(hwq * 4 + 0) * 72 + c] = (bf16_t)v4.x;
    tile[(hwq * 4 + 1) * 72 + c] = (bf16_t)v4.y;
    tile[(hwq * 4 + 2) * 72 + c] = (bf16_t)v4.z;
    tile[(hwq * 4 + 3) * 72 + c] = (bf16_t)v4.w;
  }
  __syncthreads();
  #pragma unroll
  for (int i = 0; i < 2; ++i) {
    int idx = t + 256 * i;
    int hw = idx >> 3, q = idx & 7;
    bf16x8 v8 = *(const bf16x8*)&tile[hw * 72 + q * 8];
    *(bf16x8*)(xT + ((size_t)((b * ND + d) * NHW + hw0 + hw)) * NC + c0 + q * 8) = v8;
  }
}

// ================= Kernel F: fused QKV + attention (48KB LDS) =================
// grid 2048 = (hw,b); 256 threads (4 waves); 3 blocks/CU.
__global__ __launch_bounds__(256, 3) void qkv_attn3(
    const bf16_t* __restrict__ xT, const bf16_t* __restrict__ wsW,
    const float* __restrict__ bk, const float* __restrict__ bq,
    const float* __restrict__ bv, bf16_t* __restrict__ att) {
  __shared__ bf16_t lds[24576];          // 48 KB
  bf16_t* kT   = lds;                    // [d][s] swz (8192 els)
  bf16_t* qT   = lds + 8192;             // [d][s] swz
  bf16_t* vS   = lds + 16384;            // [s][d] swz
  bf16_t* xTl  = lds;                    // [d][128c] swz (slice; dead pre-epilogue)
  bf16_t* aT   = lds;                    // [j][i] swz (4096 els; post-QK^T)
  bf16_t* attT = lds + 8192;             // [d][s] swz (post-QK^T)

  const int gid = blockIdx.x;
  const int b = gid & 7, hw = gid >> 3;
  const int t = threadIdx.x, w = t >> 6, lane = t & 63;
  const int l16 = lane & 15, q4 = lane >> 4;

  const int mat = w >> 1;
  const int sb = (w & 1) * 64;
  const bf16_t* wm = mat ? (wsW + 32768) : wsW;    // wq : wk frag
  const bf16_t* wvF = wsW + 65536;
  const float* bm = mat ? bq : bk;
  bf16_t* dstKQ = mat ? qT : kT;
  const int sbv = w * 32;

  f32x4 acc[4][4] = {};     // K-or-Q accumulator (row=s, col=d)
  f32x4 accv[4][2] = {};    // V accumulator (row=d, col=s)

  for (int cc = 0; cc < 2; ++cc) {
    __syncthreads();
    #pragma unroll
    for (int jj = 0; jj < 4; ++jj) {
      int id = jj * 256 + t;
      int d = id >> 4, cg = (id & 15) * 8;
      bf16x8 v8 = *(const bf16x8*)(xT + ((size_t)((b * ND + d) * NHW + hw)) * NC + cc * 128 + cg);
      *(bf16x8*)&xTl[d * 128 + swz(d, cg)] = v8;
    }
    __syncthreads();
    #pragma unroll
    for (int ks = 0; ks < 4; ++ks) {
      const int kb = ks * 32 + q4 * 8;
      const int kgf = ((cc * 128 + kb) >> 3) * 1024;
      bf16x8 xfr[4], afk[4], bfv[2];
      #pragma unroll
      for (int i = 0; i < 4; ++i) {
        int row = i * 16 + l16;
        xfr[i] = *(const bf16x8*)&xTl[row * 128 + swz(row, kb)];
        int s = sb + i * 16 + l16;
        afk[i] = *(const bf16x8*)(wm + kgf + s * 8);
      }
      #pragma unroll
      for (int i = 0; i < 2; ++i) {
        int s = sbv + i * 16 + l16;
        bfv[i] = *(const bf16x8*)(wvF + kgf + s * 8);
      }
      #pragma unroll
      for (int nt = 0; nt < 4; ++nt)
        #pragma unroll
        for (int mt = 0; mt < 4; ++mt)
          acc[mt][nt] = MFMA16(afk[mt], xfr[nt], acc[mt][nt], 0, 0, 0);
      #pragma unroll
      for (int nt = 0; nt < 2; ++nt)
        #pragma unroll
        for (int mt = 0; mt < 4; ++mt)
          accv[mt][nt] = MFMA16(xfr[mt], bfv[nt], accv[mt][nt], 0, 0, 0);
    }
  }
  __syncthreads();   // xTl dead; epilogue overwrites its region (kT)

  // ---- epilogue: K/Q -> kT/qT [d][s]; V -> vS [s][d] ----
  #pragma unroll
  for (int mt = 0; mt < 4; ++mt) {
    int s0 = sb + mt * 16 + q4 * 4;
    float4 b4 = *(const float4*)(bm + s0);
    #pragma unroll
    for (int nt = 0; nt < 4; ++nt) {
      int d = nt * 16 + l16;
      bf16x4 pk;
      pk[0] = (bf16_t)(acc[mt][nt][0] + b4.x);
      pk[1] = (bf16_t)(acc[mt][nt][1] + b4.y);
      pk[2] = (bf16_t)(acc[mt][nt][2] + b4.z);
      pk[3] = (bf16_t)(acc[mt][nt][3] + b4.w);
      *(bf16x4*)&dstKQ[d * NS + swz(d, s0)] = pk;
    }
  }
  #pragma unroll
  for (int nt = 0; nt < 2; ++nt) {
    int s = sbv + nt * 16 + l16;
    float bvs = bv[s];
    #pragma unroll
    for (int mt = 0; mt < 4; ++mt) {
      int d0 = mt * 16 + q4 * 4;
      bf16x4 pv;
      pv[0] = (bf16_t)(accv[mt][nt][0] + bvs);
      pv[1] = (bf16_t)(accv[mt][nt][1] + bvs);
      pv[2] = (bf16_t)(accv[mt][nt][2] + bvs);
      pv[3] = (bf16_t)(accv[mt][nt][3] + bvs);
      *(bf16x4*)&vS[s * ND + (d0 ^ ((s & 7) << 3))] = pv;
    }
  }
  __syncthreads();

  // ---- scores + softmax ----
  float ps[16];
  {
    f32x4 sacc[4] = {};
    for (int ks = 0; ks < 4; ++ks) {
      const int kb = ks * 32 + q4 * 8;
      int jrow = w * 16 + l16;
      bf16x8 bfr = *(const bf16x8*)&qT[jrow * NS + swz(jrow, kb)];
      #pragma unroll
      for (int it = 0; it < 4; ++it) {
        int irow = it * 16 + l16;
        bf16x8 afr = *(const bf16x8*)&kT[irow * NS + swz(irow, kb)];
        sacc[it] = MFMA16(afr, bfr, sacc[it], 0, 0, 0);
      }
    }
    const float scale = 0.088388347648318447f;  // 1/sqrt(128)
    float mx = -1e30f;
    #pragma unroll
    for (int it = 0; it < 4; ++it)
      #pragma unroll
      for (int r = 0; r < 4; ++r) {
        float vv = sacc[it][r] * scale;
        ps[it * 4 + r] = vv;
        mx = fmaxf(mx, vv);
      }
    mx = fmaxf(mx, __shfl_xor(mx, 16));
    mx = fmaxf(mx, __shfl_xor(mx, 32));
    float sum = 0.f;
    #pragma unroll
    for (int i = 0; i < 16; ++i) { ps[i] = __expf(ps[i] - mx); sum += ps[i]; }
    sum += __shfl_xor(sum, 16);
    sum += __shfl_xor(sum, 32);
    float inv = 1.f / sum;
    #pragma unroll
    for (int i = 0; i < 16; ++i) ps[i] *= inv;
  }
  __syncthreads();

  {
    int j = w * 16 + l16;
    #pragma unroll
    for (int it = 0; it < 4; ++it) {
      bf16x4 pk;
      #pragma unroll
      for (int r = 0; r < 4; ++r) pk[r] = (bf16_t)ps[it * 4 + r];
      *(bf16x4*)&aT[j * ND + ((it * 16 + q4 * 4) ^ ((j & 7) << 3))] = pk;
    }
  }
  __syncthreads();

  // ---- PV -> attT[j][s] ----
  {
    const int sbp = w * 32;
    f32x4 pacc[2][4] = {};
    #pragma unroll
    for (int ki = 0; ki < 2; ++ki) {
      const int kb = ki * 32 + q4 * 8;
      bf16x8 afr[2];
      #pragma unroll
      for (int mt = 0; mt < 2; ++mt) {
        int srow = sbp + mt * 16 + l16;
        afr[mt] = *(const bf16x8*)&vS[srow * ND + (kb ^ ((srow & 7) << 3))];
      }
      #pragma unroll
      for (int nt = 0; nt < 4; ++nt) {
        int jrow = nt * 16 + l16;
        bf16x8 bfr = *(const bf16x8*)&aT[jrow * ND + (kb ^ ((jrow & 7) << 3))];
        #pragma unroll
        for (int mt = 0; mt < 2; ++mt)
          pacc[mt][nt] = MFMA16(afr[mt], bfr, pacc[mt][nt], 0, 0, 0);
      }
    }
    #pragma unroll
    for (int nt = 0; nt < 4; ++nt) {
      int j = nt * 16 + l16;
      #pragma unroll
      for (int mt = 0; mt < 2; ++mt) {
        bf16x4 pk;
        #pragma unroll
        for (int r = 0; r < 4; ++r) pk[r] = (bf16_t)pacc[mt][nt][r];
        *(bf16x4*)&attT[j * NS + swz(j, sbp + mt * 16 + q4 * 4)] = pk;
      }
    }
  }
  __syncthreads();

  #pragma unroll
  for (int jj = 0; jj < 4; ++jj) {
    int f = jj * 2048 + t * 8;
    int d = f >> 7, s0 = f & 127;
    bf16x8 v8 = *(const bf16x8*)&attT[d * NS + (s0 ^ ((d & 7) << 3))];
    *(bf16x8*)(att + ((size_t)((b * ND + d) * NHW + hw)) * NS + s0) = v8;
  }
}

// ================= Kernel C: out projection + residual =================
// grid 2048 = ht(8: 32hw) * dcq(16: 4d) * ch(2: 128c) * b(8)
// A = woF (m=c), B = slab rows (n = d4*32+hw). Staged fp32 epilogue,
// 2 rounds of 64c, dense 128B float4 stores. Union LDS 33.8KB -> 4 blocks/CU.
__global__ __launch_bounds__(256, 4) void out_proj3(
    const bf16_t* __restrict__ att_ws,
    const bf16_t* __restrict__ woF, const float* __restrict__ bo,
    const float* __restrict__ x, float* __restrict__ out) {
  __shared__ union {
    bf16_t slab[128 * 128];   // rows = d4*32+hw, slot16-XOR by hw&7 (32 KB)
    float  stage[64 * 132];   // [c64][4d*32hw + 4 pad] (33.8 KB)
  } sm;
  const int bid = blockIdx.x;
  const int ht = bid & 7, dcq = (bid >> 3) & 15, ch = (bid >> 7) & 1, b = bid >> 8;
  const int t = threadIdx.x, w = t >> 6, lane = t & 63;
  const int l16 = lane & 15, g = lane >> 4;
  const int mh = w >> 1, nh = w & 1;

  // stage att -> slab (dense 1024B wave reads)
  {
    const int j = t & 15;            // s-chunk
    const int r0 = t >> 4;           // row within pass
    #pragma unroll
    for (int pp = 0; pp < 8; ++pp) {
      int row = pp * 16 + r0;
      int d = row >> 5, hw = row & 31;
      bf16x8 v8 = *(const bf16x8*)(att_ws +
          ((size_t)((b * ND + dcq * 4 + d) * NHW + ht * 32 + hw)) * NS + j * 8);
      *(bf16x8*)&sm.slab[row * NS + ((j ^ (hw & 7)) << 3)] = v8;
    }
  }
  __syncthreads();

  f32x4 acc[4][4] = {};
  #pragma unroll
  for (int kq = 0; kq < 4; ++kq) {
    bf16x8 af[4];
    #pragma unroll
    for (int mt = 0; mt < 4; ++mt) {
      int c = ch * 128 + mh * 64 + mt * 16 + l16;
      af[mt] = *(const bf16x8*)(woF + (kq * 4 + g) * 2048 + c * 8);
    }
    #pragma unroll
    for (int nt = 0; nt < 4; ++nt) {
      int row = nh * 64 + nt * 16 + l16;
      int hwl = row & 31;
      bf16x8 bfr = *(const bf16x8*)&sm.slab[row * NS + (((kq * 4 + g) ^ (hwl & 7)) << 3)];
      #pragma unroll
      for (int mt = 0; mt < 4; ++mt)
        acc[mt][nt] = MFMA16(af[mt], bfr, acc[mt][nt], 0, 0, 0);
    }
  }

  // ---- staged epilogue: two rounds of 64 c ----
  #pragma unroll
  for (int p = 0; p < 2; ++p) {
    __syncthreads();
    if (mh == p) {
      #pragma unroll
      for (int mt = 0; mt < 4; ++mt) {
        #pragma unroll
        for (int nt = 0; nt < 4; ++nt) {
          int row = nh * 64 + nt * 16 + l16;      // n = d*32 + hw
          int dl = row >> 5;
          int hws = (row & 31) ^ (g << 3);
          int base = (mt * 16 + g * 4) * 132 + dl * 32 + hws;
          #pragma unroll
          for (int r = 0; r < 4; ++r)
            sm.stage[base + r * 132] = acc[mt][nt][r];
        }
      }
    }
    __syncthreads();
    #pragma unroll
    for (int ii = 0; ii < 8; ++ii) {
      int c6 = ii * 8 + w * 2 + (lane >> 5);      // [0,64)
      int c = ch * 128 + p * 64 + c6;
      int dq = (lane >> 3) & 3;
      int hw4 = (lane & 7) * 4;
      float4 v = *(const float4*)&sm.stage[c6 * 132 + dq * 32 + (hw4 ^ (((c6 >> 2) & 3) << 3))];
      size_t gi = ((size_t)(b * NC + c) * ND + dcq * 4 + dq) * NHW + ht * 32 + hw4;
      float4 xv = *(const float4*)(x + gi);
      float bias = bo[c];
      float4 o;
      o.x = v.x + bias + xv.x;
      o.y = v.y + bias + xv.y;
      o.z = v.z + bias + xv.z;
      o.w = v.w + bias + xv.w;
      *(float4*)(out + gi) = o;
    }
  }
}

// ================= Fallback: round-1 fused kernel =================
struct SMemF {
  union {
    bf16_t xT[ND * NC];
    struct { bf16_t aT[ND * ND]; bf16_t attT[ND * NS]; } p2;
  } u;
  bf16_t kT[ND * NS];
  bf16_t qT[ND * NS];
  bf16_t vS[NS * ND];
};

__global__ __launch_bounds__(256) void attn_fused(
    const float* __restrict__ x,
    const float* __restrict__ wk, const float* __restrict__ bk,
    const float* __restrict__ wq, const float* __restrict__ bq,
    const float* __restrict__ wv, const float* __restrict__ bv,
    const float* __restrict__ wo, const float* __restrict__ bo,
    float* __restrict__ out) {
  __shared__ SMemF sm;
  const int gid = blockIdx.x;
  const int b = gid & 7;
  const int hw = gid >> 3;
  const int t = threadIdx.x;
  const int w = t >> 6;
  const int lane = t & 63;
  const int l16 = lane & 15;
  const int q4 = lane >> 4;
  const float* xb = x + (size_t)b * NC * ND * NHW + hw;
  {
    const int d = t & 63;
    const int cb = (t >> 6) * 64;
    for (int jj = 0; jj < 8; ++jj) {
      bf16x8 pk;
      #pragma unroll
      for (int e = 0; e < 8; ++e) {
        int c = cb + jj * 8 + e;
        pk[e] = (bf16_t)xb[(size_t)(c * ND + d) * NHW];
      }
      *(bf16x8*)&sm.u.xT[d * NC + swz(d, cb + jj * 8)] = pk;
    }
  }
  __syncthreads();
  {
    const int mat = w >> 1;
    const int sb = (w & 1) * 64;
    const float* wm = mat ? wq : wk;
    const float* bm = mat ? bq : bk;
    bf16_t* dst = mat ? sm.qT : sm.kT;
    f32x4 acc[4][4] = {};
    for (int ks = 0; ks < 8; ++ks) {
      const int kb = ks * 32 + q4 * 8;
      bf16x8 afr[4];
      #pragma unroll
      for (int mt = 0; mt < 4; ++mt) {
        int row = mt * 16 + l16;
        afr[mt] = *(const bf16x8*)&sm.u.xT[row * NC + swz(row, kb)];
      }
      #pragma unroll
      for (int st = 0; st < 4; ++st) {
        int s = sb + st * 16 + l16;
        bf16x8 bfr = ldg_w8(wm + s * NC + kb);
        #pragma unroll
        for (int mt = 0; mt < 4; ++mt)
          acc[mt][st] = MFMA16(afr[mt], bfr, acc[mt][st], 0, 0, 0);
      }
    }
    #pragma unroll
    for (int st = 0; st < 4; ++st) {
      int s = sb + st * 16 + l16;
      float bias = bm[s];
      #pragma unroll
      for (int mt = 0; mt < 4; ++mt) {
        #pragma unroll
        for (int r = 0; r < 4; ++r) {
          int d = mt * 16 + q4 * 4 + r;
          dst[d * NS + swz(d, s)] = (bf16_t)(acc[mt][st][r] + bias);
        }
      }
    }
  }
  {
    const int sb = w * 32;
    f32x4 acc[2][4] = {};
    for (int ks = 0; ks < 8; ++ks) {
      const int kb = ks * 32 + q4 * 8;
      bf16x8 afr[2];
      #pragma unroll
      for (int mt = 0; mt < 2; ++mt)
        afr[mt] = ldg_w8(wv + (sb + mt * 16 + l16) * NC + kb);
      #pragma unroll
      for (int nt = 0; nt < 4; ++nt) {
        int row = nt * 16 + l16;
        bf16x8 bfr = *(const bf16x8*)&sm.u.xT[row * NC + swz(row, kb)];
        #pragma unroll
        for (int mt = 0; mt < 2; ++mt)
          acc[mt][nt] = MFMA16(afr[mt], bfr, acc[mt][nt], 0, 0, 0);
      }
    }
    #pragma unroll
    for (int mt = 0; mt < 2; ++mt) {
      #pragma unroll
      for (int r = 0; r < 4; ++r) {
        int s = sb + mt * 16 + q4 * 4 + r;
        float bias = bv[s];
        #pragma unroll
        for (int nt = 0; nt < 4; ++nt) {
          int d = nt * 16 + l16;
          sm.vS[s * ND + swz(s, d)] = (bf16_t)(acc[mt][nt][r] + bias);
        }
      }
    }
  }
  __syncthreads();
  {
    f32x4 sacc[4] = {};
    for (int ks = 0; ks < 4; ++ks) {
      const int kb = ks * 32 + q4 * 8;
      int jrow = w * 16 + l16;
      bf16x8 bfr = *(const bf16x8*)&sm.qT[jrow * NS + swz(jrow, kb)];
      #pragma unroll
      for (int it = 0; it < 4; ++it) {
        int irow = it * 16 + l16;
        bf16x8 afr = *(const bf16x8*)&sm.kT[irow * NS + swz(irow, kb)];
        sacc[it] = MFMA16(afr, bfr, sacc[it], 0, 0, 0);
      }
    }
    const float scale = 0.088388347648318447f;
    float ps[16];
    float mx = -1e30f;
    #pragma unroll
    for (int it = 0; it < 4; ++it) {
      #pragma unroll
      for (int r = 0; r < 4; ++r) {
        float vv = sacc[it][r] * scale;
        ps[it * 4 + r] = vv;
        mx = fmaxf(mx, vv);
      }
    }
    mx = fmaxf(mx, __shfl_xor(mx, 16));
    mx = fmaxf(mx, __shfl_xor(mx, 32));
    float sum = 0.f;
    #pragma unroll
    for (int i = 0; i < 16; ++i) { ps[i] = __expf(ps[i] - mx); sum += ps[i]; }
    sum += __shfl_xor(sum, 16);
    sum += __shfl_xor(sum, 32);
    float inv = 1.f / sum;
    int j = w * 16 + l16;
    #pragma unroll
    for (int it = 0; it < 4; ++it) {
      bf16x4 pk;
      #pragma unroll
      for (int r = 0; r < 4; ++r) pk[r] = (bf16_t)(ps[it * 4 + r] * inv);
      *(bf16x4*)&sm.u.p2.aT[j * ND + swz(j, it * 16 + q4 * 4)] = pk;
    }
  }
  __syncthreads();
  {
    const int sb = w * 32;
    f32x4 acc[2][4] = {};
    #pragma unroll
    for (int ki = 0; ki < 2; ++ki) {
      const int kb = ki * 32 + q4 * 8;
      bf16x8 afr[2];
      #pragma unroll
      for (int mt = 0; mt < 2; ++mt) {
        int srow = sb + mt * 16 + l16;
        afr[mt] = *(const bf16x8*)&sm.vS[srow * ND + swz(srow, kb)];
      }
      #pragma unroll
      for (int nt = 0; nt < 4; ++nt) {
        int jrow = nt * 16 + l16;
        bf16x8 bfr = *(const bf16x8*)&sm.u.p2.aT[jrow * ND + swz(jrow, kb)];
        #pragma unroll
        for (int mt = 0; mt < 2; ++mt)
          acc[mt][nt] = MFMA16(afr[mt], bfr, acc[mt][nt], 0, 0, 0);
      }
    }
    #pragma unroll
    for (int nt = 0; nt < 4; ++nt) {
      int j = nt * 16 + l16;
      #pragma unroll
      for (int mt = 0; mt < 2; ++mt) {
        bf16x4 pk;
        #pragma unroll
        for (int r = 0; r < 4; ++r) pk[r] = (bf16_t)acc[mt][nt][r];
        *(bf16x4*)&sm.u.p2.attT[j * NS + swz(j, sb + mt * 16 + q4 * 4)] = pk;
      }
    }
  }
  __syncthreads();
  {
    const int cb = w * 64;
    f32x4 acc[4][4] = {};
    for (int ks = 0; ks < 4; ++ks) {
      const int kb = ks * 32 + q4 * 8;
      bf16x8 afr[4];
      #pragma unroll
      for (int mt = 0; mt < 4; ++mt)
        afr[mt] = ldg_w8(wo + (cb + mt * 16 + l16) * NS + kb);
      #pragma unroll
      for (int nt = 0; nt < 4; ++nt) {
        int jrow = nt * 16 + l16;
        bf16x8 bfr = *(const bf16x8*)&sm.u.p2.attT[jrow * NS + swz(jrow, kb)];
        #pragma unroll
        for (int mt = 0; mt < 4; ++mt)
          acc[mt][nt] = MFMA16(afr[mt], bfr, acc[mt][nt], 0, 0, 0);
      }
    }
    #pragma unroll
    for (int mt = 0; mt < 4; ++mt) {
      #pragma unroll
      for (int r = 0; r < 4; ++r) {
        int c = cb + mt * 16 + q4 * 4 + r;
        float bias = bo[c];
        #pragma unroll
        for (int nt = 0; nt < 4; ++nt) {
          int d = nt * 16 + l16;
          size_t gi = (size_t)(((b * NC + c) * ND + d) * NHW + hw);
          out[gi] = acc[mt][nt][r] + bias + x[gi];
        }
      }
    }
  }
}

extern "C" void kernel_launch(void* const* d_in, const int* in_sizes, int n_in,
                              void* d_out, int out_size, void* d_ws, size_t ws_size,
                              hipStream_t stream) {
  const float* x  = (const float*)d_in[0];
  const float* wk = (const float*)d_in[1];
  const float* bk = (const float*)d_in[2];
  const float* wq = (const float*)d_in[3];
  const float* bq = (const float*)d_in[4];
  const float* wv = (const float*)d_in[5];
  const float* bv = (const float*)d_in[6];
  const float* wo = (const float*)d_in[7];
  const float* bo = (const float*)d_in[8];
  float* out = (float*)d_out;

  // ws: [weights bf16 131072 el | xT 33554432 el | att 16777216 el]
  const size_t need = (size_t)(131072 + 33554432 + 16777216) * 2;
  if (ws_size >= need) {
    bf16_t* wsW = (bf16_t*)d_ws;
    bf16_t* xT  = wsW + 131072;
    bf16_t* att = xT + 33554432;
    transpose_x_w<<<dim3(8224), dim3(256), 0, stream>>>(x, wk, wq, wv, wo, xT, wsW);
    qkv_attn3<<<dim3(2048), dim3(256), 0, stream>>>(xT, wsW, bk, bq, bv, att);
    out_proj3<<<dim3(2048), dim3(256), 0, stream>>>(att, wsW + 98304, bo, x, out);
  } else {
    attn_fused<<<dim3(2048), dim3(256), 0, stream>>>(x, wk, bk, wq, bq, wv, bv, wo, bo, out);
  }
}

// Round 9
// 130.922 us; speedup vs baseline: 1.3308x; 1.0273x over previous
//
#include <hip/hip_runtime.h>
#include <hip/hip_bf16.h>

// 3-kernel pipeline:
//   T: x [b][c][d][hw] fp32 -> xT [b][d][hw][c] bf16; weights -> fragmented bf16
//   F: fused QKV + per-(b,hw) attention, 48KB LDS, 3 blocks/CU.
//      att -> [b][d][hw][s] bf16.
//   C: out-projection + bias + residual. 64c x 4d x 32hw block (grid 4096),
//      single-round staged fp32 epilogue, register-prefetched residual,
//      dense 128B float4 stores. 33.8KB LDS -> 4 blocks/CU.
// Fallback: round-1 fused kernel if workspace too small.

typedef __bf16 bf16_t;
typedef bf16_t bf16x8 __attribute__((ext_vector_type(8)));
typedef bf16_t bf16x4 __attribute__((ext_vector_type(4)));
typedef float  f32x4  __attribute__((ext_vector_type(4)));

#define NB   8
#define NC   256
#define ND   64
#define NHW  256
#define NS   128

#define MFMA16 __builtin_amdgcn_mfma_f32_16x16x32_bf16

__device__ __forceinline__ int swz(int row, int col) {
  return col ^ ((row & 7) << 3);
}

__device__ __forceinline__ bf16x8 pack8(float4 a, float4 b) {
  bf16x8 r;
  r[0] = (bf16_t)a.x; r[1] = (bf16_t)a.y; r[2] = (bf16_t)a.z; r[3] = (bf16_t)a.w;
  r[4] = (bf16_t)b.x; r[5] = (bf16_t)b.y; r[6] = (bf16_t)b.z; r[7] = (bf16_t)b.w;
  return r;
}

__device__ __forceinline__ bf16x8 ldg_w8(const float* p) {
  float4 a = *(const float4*)p;
  float4 b = *(const float4*)(p + 4);
  return pack8(a, b);
}

// ================= Kernel T: transpose x -> xT bf16; fragment weights ========
// grid 8224: [0,8192): 64c x 64hw tile per (b,d); [8192,8224): weights
__global__ __launch_bounds__(256) void transpose_x_w(
    const float* __restrict__ x,
    const float* __restrict__ wk, const float* __restrict__ wq,
    const float* __restrict__ wv, const float* __restrict__ wo,
    bf16_t* __restrict__ xT, bf16_t* __restrict__ wsW) {
  __shared__ bf16_t tile[64 * 72];   // [hw][c] pad to 72
  const int bid = blockIdx.x;
  if (bid >= 8192) {
    const int wid = bid - 8192;
    const int mat = wid >> 3, sub = wid & 7;
    const int t = threadIdx.x;
    if (mat < 3) {
      // wk/wq/wv [128 s][256 c] -> frag [32 cg][128 s][8]
      const float* src = (mat == 0) ? wk : (mat == 1) ? wq : wv;
      bf16_t* dst = wsW + mat * 32768;
      int s = sub * 16 + (t >> 4), c0 = (t & 15) * 16;
      const float* p = src + s * NC + c0;
      float4 a0 = *(const float4*)p, a1 = *(const float4*)(p + 4);
      float4 a2 = *(const float4*)(p + 8), a3 = *(const float4*)(p + 12);
      *(bf16x8*)(dst + (c0 >> 3) * 1024 + s * 8)       = pack8(a0, a1);
      *(bf16x8*)(dst + ((c0 >> 3) + 1) * 1024 + s * 8) = pack8(a2, a3);
    } else {
      // wo [256 c][128 s] -> frag [16 sg][256 c][8]
      bf16_t* dst = wsW + 98304;
      int c = sub * 32 + (t >> 3), sc0 = (t & 7) * 16;
      const float* p = wo + c * NS + sc0;
      float4 a0 = *(const float4*)p, a1 = *(const float4*)(p + 4);
      float4 a2 = *(const float4*)(p + 8), a3 = *(const float4*)(p + 12);
      *(bf16x8*)(dst + (sc0 >> 3) * 2048 + c * 8)       = pack8(a0, a1);
      *(bf16x8*)(dst + ((sc0 >> 3) + 1) * 2048 + c * 8) = pack8(a2, a3);
    }
    return;
  }
  const int ct = bid & 3, hwt = (bid >> 2) & 3;
  const int d = (bid >> 4) & 63, b = bid >> 10;
  const int c0 = ct * 64, hw0 = hwt * 64;
  const int t = threadIdx.x;
  const int hwq = t & 15, chi = t >> 4;

  #pragma unroll
  for (int q = 0; q < 4; ++q) {
    int c = q * 16 + chi;
    float4 v4 = *(const float4*)(x + ((size_t)((b * NC + c0 + c) * ND + d)) * NHW + hw0 + hwq * 4);
    tile[(hwq * 4 + 0) * 72 + c] = (bf16_t)v4.x;
    tile[(hwq * 4 + 1) * 72 + c] = (bf16_t)v4.y;
    tile[(hwq * 4 + 2) * 72 + c] = (bf16_t)v4.z;
    tile[(hwq * 4 + 3) * 72 + c] = (bf16_t)v4.w;
  }
  __syncthreads();
  #pragma unroll
  for (int i = 0; i < 2; ++i) {
    int idx = t + 256 * i;
    int hw = idx >> 3, q = idx & 7;
    bf16x8 v8 = *(const bf16x8*)&tile[hw * 72 + q * 8];
    *(bf16x8*)(xT + ((size_t)((b * ND + d) * NHW + hw0 + hw)) * NC + c0 + q * 8) = v8;
  }
}

// ================= Kernel F: fused QKV + attention (48KB LDS) =================
// grid 2048 = (hw,b); 256 threads (4 waves); 3 blocks/CU.
__global__ __launch_bounds__(256, 3) void qkv_attn3(
    const bf16_t* __restrict__ xT, const bf16_t* __restrict__ wsW,
    const float* __restrict__ bk, const float* __restrict__ bq,
    const float* __restrict__ bv, bf16_t* __restrict__ att) {
  __shared__ bf16_t lds[24576];          // 48 KB
  bf16_t* kT   = lds;                    // [d][s] swz (8192 els)
  bf16_t* qT   = lds + 8192;             // [d][s] swz
  bf16_t* vS   = lds + 16384;            // [s][d] swz
  bf16_t* xTl  = lds;                    // [d][128c] swz (slice; dead pre-epilogue)
  bf16_t* aT   = lds;                    // [j][i] swz (4096 els; post-QK^T)
  bf16_t* attT = lds + 8192;             // [d][s] swz (post-QK^T)

  const int gid = blockIdx.x;
  const int b = gid & 7, hw = gid >> 3;
  const int t = threadIdx.x, w = t >> 6, lane = t & 63;
  const int l16 = lane & 15, q4 = lane >> 4;

  const int mat = w >> 1;
  const int sb = (w & 1) * 64;
  const bf16_t* wm = mat ? (wsW + 32768) : wsW;    // wq : wk frag
  const bf16_t* wvF = wsW + 65536;
  const float* bm = mat ? bq : bk;
  bf16_t* dstKQ = mat ? qT : kT;
  const int sbv = w * 32;

  f32x4 acc[4][4] = {};     // K-or-Q accumulator (row=s, col=d)
  f32x4 accv[4][2] = {};    // V accumulator (row=d, col=s)

  for (int cc = 0; cc < 2; ++cc) {
    __syncthreads();
    #pragma unroll
    for (int jj = 0; jj < 4; ++jj) {
      int id = jj * 256 + t;
      int d = id >> 4, cg = (id & 15) * 8;
      bf16x8 v8 = *(const bf16x8*)(xT + ((size_t)((b * ND + d) * NHW + hw)) * NC + cc * 128 + cg);
      *(bf16x8*)&xTl[d * 128 + swz(d, cg)] = v8;
    }
    __syncthreads();
    #pragma unroll
    for (int ks = 0; ks < 4; ++ks) {
      const int kb = ks * 32 + q4 * 8;
      const int kgf = ((cc * 128 + kb) >> 3) * 1024;
      bf16x8 xfr[4], afk[4], bfv[2];
      #pragma unroll
      for (int i = 0; i < 4; ++i) {
        int row = i * 16 + l16;
        xfr[i] = *(const bf16x8*)&xTl[row * 128 + swz(row, kb)];
        int s = sb + i * 16 + l16;
        afk[i] = *(const bf16x8*)(wm + kgf + s * 8);
      }
      #pragma unroll
      for (int i = 0; i < 2; ++i) {
        int s = sbv + i * 16 + l16;
        bfv[i] = *(const bf16x8*)(wvF + kgf + s * 8);
      }
      #pragma unroll
      for (int nt = 0; nt < 4; ++nt)
        #pragma unroll
        for (int mt = 0; mt < 4; ++mt)
          acc[mt][nt] = MFMA16(afk[mt], xfr[nt], acc[mt][nt], 0, 0, 0);
      #pragma unroll
      for (int nt = 0; nt < 2; ++nt)
        #pragma unroll
        for (int mt = 0; mt < 4; ++mt)
          accv[mt][nt] = MFMA16(xfr[mt], bfv[nt], accv[mt][nt], 0, 0, 0);
    }
  }
  __syncthreads();   // xTl dead; epilogue overwrites its region (kT)

  // ---- epilogue: K/Q -> kT/qT [d][s]; V -> vS [s][d] ----
  #pragma unroll
  for (int mt = 0; mt < 4; ++mt) {
    int s0 = sb + mt * 16 + q4 * 4;
    float4 b4 = *(const float4*)(bm + s0);
    #pragma unroll
    for (int nt = 0; nt < 4; ++nt) {
      int d = nt * 16 + l16;
      bf16x4 pk;
      pk[0] = (bf16_t)(acc[mt][nt][0] + b4.x);
      pk[1] = (bf16_t)(acc[mt][nt][1] + b4.y);
      pk[2] = (bf16_t)(acc[mt][nt][2] + b4.z);
      pk[3] = (bf16_t)(acc[mt][nt][3] + b4.w);
      *(bf16x4*)&dstKQ[d * NS + swz(d, s0)] = pk;
    }
  }
  #pragma unroll
  for (int nt = 0; nt < 2; ++nt) {
    int s = sbv + nt * 16 + l16;
    float bvs = bv[s];
    #pragma unroll
    for (int mt = 0; mt < 4; ++mt) {
      int d0 = mt * 16 + q4 * 4;
      bf16x4 pv;
      pv[0] = (bf16_t)(accv[mt][nt][0] + bvs);
      pv[1] = (bf16_t)(accv[mt][nt][1] + bvs);
      pv[2] = (bf16_t)(accv[mt][nt][2] + bvs);
      pv[3] = (bf16_t)(accv[mt][nt][3] + bvs);
      *(bf16x4*)&vS[s * ND + (d0 ^ ((s & 7) << 3))] = pv;
    }
  }
  __syncthreads();

  // ---- scores + softmax ----
  float ps[16];
  {
    f32x4 sacc[4] = {};
    for (int ks = 0; ks < 4; ++ks) {
      const int kb = ks * 32 + q4 * 8;
      int jrow = w * 16 + l16;
      bf16x8 bfr = *(const bf16x8*)&qT[jrow * NS + swz(jrow, kb)];
      #pragma unroll
      for (int it = 0; it < 4; ++it) {
        int irow = it * 16 + l16;
        bf16x8 afr = *(const bf16x8*)&kT[irow * NS + swz(irow, kb)];
        sacc[it] = MFMA16(afr, bfr, sacc[it], 0, 0, 0);
      }
    }
    const float scale = 0.088388347648318447f;  // 1/sqrt(128)
    float mx = -1e30f;
    #pragma unroll
    for (int it = 0; it < 4; ++it)
      #pragma unroll
      for (int r = 0; r < 4; ++r) {
        float vv = sacc[it][r] * scale;
        ps[it * 4 + r] = vv;
        mx = fmaxf(mx, vv);
      }
    mx = fmaxf(mx, __shfl_xor(mx, 16));
    mx = fmaxf(mx, __shfl_xor(mx, 32));
    float sum = 0.f;
    #pragma unroll
    for (int i = 0; i < 16; ++i) { ps[i] = __expf(ps[i] - mx); sum += ps[i]; }
    sum += __shfl_xor(sum, 16);
    sum += __shfl_xor(sum, 32);
    float inv = 1.f / sum;
    #pragma unroll
    for (int i = 0; i < 16; ++i) ps[i] *= inv;
  }
  __syncthreads();

  {
    int j = w * 16 + l16;
    #pragma unroll
    for (int it = 0; it < 4; ++it) {
      bf16x4 pk;
      #pragma unroll
      for (int r = 0; r < 4; ++r) pk[r] = (bf16_t)ps[it * 4 + r];
      *(bf16x4*)&aT[j * ND + ((it * 16 + q4 * 4) ^ ((j & 7) << 3))] = pk;
    }
  }
  __syncthreads();

  // ---- PV -> attT[j][s] ----
  {
    const int sbp = w * 32;
    f32x4 pacc[2][4] = {};
    #pragma unroll
    for (int ki = 0; ki < 2; ++ki) {
      const int kb = ki * 32 + q4 * 8;
      bf16x8 afr[2];
      #pragma unroll
      for (int mt = 0; mt < 2; ++mt) {
        int srow = sbp + mt * 16 + l16;
        afr[mt] = *(const bf16x8*)&vS[srow * ND + (kb ^ ((srow & 7) << 3))];
      }
      #pragma unroll
      for (int nt = 0; nt < 4; ++nt) {
        int jrow = nt * 16 + l16;
        bf16x8 bfr = *(const bf16x8*)&aT[jrow * ND + (kb ^ ((jrow & 7) << 3))];
        #pragma unroll
        for (int mt = 0; mt < 2; ++mt)
          pacc[mt][nt] = MFMA16(afr[mt], bfr, pacc[mt][nt], 0, 0, 0);
      }
    }
    #pragma unroll
    for (int nt = 0; nt < 4; ++nt) {
      int j = nt * 16 + l16;
      #pragma unroll
      for (int mt = 0; mt < 2; ++mt) {
        bf16x4 pk;
        #pragma unroll
        for (int r = 0; r < 4; ++r) pk[r] = (bf16_t)pacc[mt][nt][r];
        *(bf16x4*)&attT[j * NS + swz(j, sbp + mt * 16 + q4 * 4)] = pk;
      }
    }
  }
  __syncthreads();

  #pragma unroll
  for (int jj = 0; jj < 4; ++jj) {
    int f = jj * 2048 + t * 8;
    int d = f >> 7, s0 = f & 127;
    bf16x8 v8 = *(const bf16x8*)&attT[d * NS + (s0 ^ ((d & 7) << 3))];
    *(bf16x8*)(att + ((size_t)((b * ND + d) * NHW + hw)) * NS + s0) = v8;
  }
}

// ================= Kernel C: out projection + residual =================
// grid 4096 = ht(8: 32hw) * dcq(16: 4d) * cq(4: 64c) * b(8)
// A = woF (m=c), B = slab rows (n = d4*32+hw). Single-round staged epilogue:
// all waves stage acc -> fp32 LDS; x residual prefetched into registers under
// the stage/barrier; dense 128B float4 stores. 33.8KB LDS -> 4 blocks/CU.
__global__ __launch_bounds__(256, 4) void out_proj4(
    const bf16_t* __restrict__ att_ws,
    const bf16_t* __restrict__ woF, const float* __restrict__ bo,
    const float* __restrict__ x, float* __restrict__ out) {
  __shared__ union {
    bf16_t slab[128 * 128];   // rows = d4*32+hw, slot16-XOR by hw&7 (32 KB)
    float  stage[64 * 132];   // [c64][4d*32hw + 4 pad] (33.8 KB)
  } sm;
  const int bid = blockIdx.x;
  const int ht = bid & 7, dcq = (bid >> 3) & 15, cq = (bid >> 7) & 3, b = bid >> 9;
  const int t = threadIdx.x, w = t >> 6, lane = t & 63;
  const int l16 = lane & 15, g = lane >> 4;
  const int mh = w >> 1, nh = w & 1;

  // stage att -> slab (dense 1024B wave reads)
  {
    const int j = t & 15;            // s-chunk
    const int r0 = t >> 4;           // row within pass
    #pragma unroll
    for (int pp = 0; pp < 8; ++pp) {
      int row = pp * 16 + r0;
      int d = row >> 5, hw = row & 31;
      bf16x8 v8 = *(const bf16x8*)(att_ws +
          ((size_t)((b * ND + dcq * 4 + d) * NHW + ht * 32 + hw)) * NS + j * 8);
      *(bf16x8*)&sm.slab[row * NS + ((j ^ (hw & 7)) << 3)] = v8;
    }
  }
  __syncthreads();

  f32x4 acc[2][4] = {};
  #pragma unroll
  for (int kq = 0; kq < 4; ++kq) {
    bf16x8 af[2];
    #pragma unroll
    for (int mt = 0; mt < 2; ++mt) {
      int c = cq * 64 + mh * 32 + mt * 16 + l16;
      af[mt] = *(const bf16x8*)(woF + (kq * 4 + g) * 2048 + c * 8);
    }
    #pragma unroll
    for (int nt = 0; nt < 4; ++nt) {
      int row = nh * 64 + nt * 16 + l16;
      int hwl = row & 31;
      bf16x8 bfr = *(const bf16x8*)&sm.slab[row * NS + (((kq * 4 + g) ^ (hwl & 7)) << 3)];
      #pragma unroll
      for (int mt = 0; mt < 2; ++mt)
        acc[mt][nt] = MFMA16(af[mt], bfr, acc[mt][nt], 0, 0, 0);
    }
  }

  // ---- prefetch residual x into registers (overlaps stage + barriers) ----
  float4 xv[8];
  size_t gis[8];
  #pragma unroll
  for (int ii = 0; ii < 8; ++ii) {
    int c6 = ii * 8 + w * 2 + (lane >> 5);
    int c = cq * 64 + c6;
    int dq = (lane >> 3) & 3;
    int hw4 = (lane & 7) * 4;
    gis[ii] = ((size_t)(b * NC + c) * ND + dcq * 4 + dq) * NHW + ht * 32 + hw4;
    xv[ii] = *(const float4*)(x + gis[ii]);
  }

  // ---- single-round staged epilogue ----
  __syncthreads();   // all slab reads done; stage overlays slab
  #pragma unroll
  for (int mt = 0; mt < 2; ++mt) {
    #pragma unroll
    for (int nt = 0; nt < 4; ++nt) {
      int row = nh * 64 + nt * 16 + l16;          // n = d*32 + hw
      int dl = row >> 5;
      int hws = (row & 31) ^ (g << 3);
      int base = (mh * 32 + mt * 16 + g * 4) * 132 + dl * 32 + hws;
      #pragma unroll
      for (int r = 0; r < 4; ++r)
        sm.stage[base + r * 132] = acc[mt][nt][r];
    }
  }
  __syncthreads();
  #pragma unroll
  for (int ii = 0; ii < 8; ++ii) {
    int c6 = ii * 8 + w * 2 + (lane >> 5);        // [0,64)
    int c = cq * 64 + c6;
    int dq = (lane >> 3) & 3;
    int hw4 = (lane & 7) * 4;
    float4 v = *(const float4*)&sm.stage[c6 * 132 + dq * 32 + (hw4 ^ (((c6 >> 2) & 3) << 3))];
    float bias = bo[c];
    float4 o;
    o.x = v.x + bias + xv[ii].x;
    o.y = v.y + bias + xv[ii].y;
    o.z = v.z + bias + xv[ii].z;
    o.w = v.w + bias + xv[ii].w;
    *(float4*)(out + gis[ii]) = o;
  }
}

// ================= Fallback: round-1 fused kernel =================
struct SMemF {
  union {
    bf16_t xT[ND * NC];
    struct { bf16_t aT[ND * ND]; bf16_t attT[ND * NS]; } p2;
  } u;
  bf16_t kT[ND * NS];
  bf16_t qT[ND * NS];
  bf16_t vS[NS * ND];
};

__global__ __launch_bounds__(256) void attn_fused(
    const float* __restrict__ x,
    const float* __restrict__ wk, const float* __restrict__ bk,
    const float* __restrict__ wq, const float* __restrict__ bq,
    const float* __restrict__ wv, const float* __restrict__ bv,
    const float* __restrict__ wo, const float* __restrict__ bo,
    float* __restrict__ out) {
  __shared__ SMemF sm;
  const int gid = blockIdx.x;
  const int b = gid & 7;
  const int hw = gid >> 3;
  const int t = threadIdx.x;
  const int w = t >> 6;
  const int lane = t & 63;
  const int l16 = lane & 15;
  const int q4 = lane >> 4;
  const float* xb = x + (size_t)b * NC * ND * NHW + hw;
  {
    const int d = t & 63;
    const int cb = (t >> 6) * 64;
    for (int jj = 0; jj < 8; ++jj) {
      bf16x8 pk;
      #pragma unroll
      for (int e = 0; e < 8; ++e) {
        int c = cb + jj * 8 + e;
        pk[e] = (bf16_t)xb[(size_t)(c * ND + d) * NHW];
      }
      *(bf16x8*)&sm.u.xT[d * NC + swz(d, cb + jj * 8)] = pk;
    }
  }
  __syncthreads();
  {
    const int mat = w >> 1;
    const int sb = (w & 1) * 64;
    const float* wm = mat ? wq : wk;
    const float* bm = mat ? bq : bk;
    bf16_t* dst = mat ? sm.qT : sm.kT;
    f32x4 acc[4][4] = {};
    for (int ks = 0; ks < 8; ++ks) {
      const int kb = ks * 32 + q4 * 8;
      bf16x8 afr[4];
      #pragma unroll
      for (int mt = 0; mt < 4; ++mt) {
        int row = mt * 16 + l16;
        afr[mt] = *(const bf16x8*)&sm.u.xT[row * NC + swz(row, kb)];
      }
      #pragma unroll
      for (int st = 0; st < 4; ++st) {
        int s = sb + st * 16 + l16;
        bf16x8 bfr = ldg_w8(wm + s * NC + kb);
        #pragma unroll
        for (int mt = 0; mt < 4; ++mt)
          acc[mt][st] = MFMA16(afr[mt], bfr, acc[mt][st], 0, 0, 0);
      }
    }
    #pragma unroll
    for (int st = 0; st < 4; ++st) {
      int s = sb + st * 16 + l16;
      float bias = bm[s];
      #pragma unroll
      for (int mt = 0; mt < 4; ++mt) {
        #pragma unroll
        for (int r = 0; r < 4; ++r) {
          int d = mt * 16 + q4 * 4 + r;
          dst[d * NS + swz(d, s)] = (bf16_t)(acc[mt][st][r] + bias);
        }
      }
    }
  }
  {
    const int sb = w * 32;
    f32x4 acc[2][4] = {};
    for (int ks = 0; ks < 8; ++ks) {
      const int kb = ks * 32 + q4 * 8;
      bf16x8 afr[2];
      #pragma unroll
      for (int mt = 0; mt < 2; ++mt)
        afr[mt] = ldg_w8(wv + (sb + mt * 16 + l16) * NC + kb);
      #pragma unroll
      for (int nt = 0; nt < 4; ++nt) {
        int row = nt * 16 + l16;
        bf16x8 bfr = *(const bf16x8*)&sm.u.xT[row * NC + swz(row, kb)];
        #pragma unroll
        for (int mt = 0; mt < 2; ++mt)
          acc[mt][nt] = MFMA16(afr[mt], bfr, acc[mt][nt], 0, 0, 0);
      }
    }
    #pragma unroll
    for (int mt = 0; mt < 2; ++mt) {
      #pragma unroll
      for (int r = 0; r < 4; ++r) {
        int s = sb + mt * 16 + q4 * 4 + r;
        float bias = bv[s];
        #pragma unroll
        for (int nt = 0; nt < 4; ++nt) {
          int d = nt * 16 + l16;
          sm.vS[s * ND + swz(s, d)] = (bf16_t)(acc[mt][nt][r] + bias);
        }
      }
    }
  }
  __syncthreads();
  {
    f32x4 sacc[4] = {};
    for (int ks = 0; ks < 4; ++ks) {
      const int kb = ks * 32 + q4 * 8;
      int jrow = w * 16 + l16;
      bf16x8 bfr = *(const bf16x8*)&sm.qT[jrow * NS + swz(jrow, kb)];
      #pragma unroll
      for (int it = 0; it < 4; ++it) {
        int irow = it * 16 + l16;
        bf16x8 afr = *(const bf16x8*)&sm.kT[irow * NS + swz(irow, kb)];
        sacc[it] = MFMA16(afr, bfr, sacc[it], 0, 0, 0);
      }
    }
    const float scale = 0.088388347648318447f;
    float ps[16];
    float mx = -1e30f;
    #pragma unroll
    for (int it = 0; it < 4; ++it) {
      #pragma unroll
      for (int r = 0; r < 4; ++r) {
        float vv = sacc[it][r] * scale;
        ps[it * 4 + r] = vv;
        mx = fmaxf(mx, vv);
      }
    }
    mx = fmaxf(mx, __shfl_xor(mx, 16));
    mx = fmaxf(mx, __shfl_xor(mx, 32));
    float sum = 0.f;
    #pragma unroll
    for (int i = 0; i < 16; ++i) { ps[i] = __expf(ps[i] - mx); sum += ps[i]; }
    sum += __shfl_xor(sum, 16);
    sum += __shfl_xor(sum, 32);
    float inv = 1.f / sum;
    int j = w * 16 + l16;
    #pragma unroll
    for (int it = 0; it < 4; ++it) {
      bf16x4 pk;
      #pragma unroll
      for (int r = 0; r < 4; ++r) pk[r] = (bf16_t)(ps[it * 4 + r] * inv);
      *(bf16x4*)&sm.u.p2.aT[j * ND + swz(j, it * 16 + q4 * 4)] = pk;
    }
  }
  __syncthreads();
  {
    const int sb = w * 32;
    f32x4 acc[2][4] = {};
    #pragma unroll
    for (int ki = 0; ki < 2; ++ki) {
      const int kb = ki * 32 + q4 * 8;
      bf16x8 afr[2];
      #pragma unroll
      for (int mt = 0; mt < 2; ++mt) {
        int srow = sb + mt * 16 + l16;
        afr[mt] = *(const bf16x8*)&sm.vS[srow * ND + swz(srow, kb)];
      }
      #pragma unroll
      for (int nt = 0; nt < 4; ++nt) {
        int jrow = nt * 16 + l16;
        bf16x8 bfr = *(const bf16x8*)&sm.u.p2.aT[jrow * ND + swz(jrow, kb)];
        #pragma unroll
        for (int mt = 0; mt < 2; ++mt)
          acc[mt][nt] = MFMA16(afr[mt], bfr, acc[mt][nt], 0, 0, 0);
      }
    }
    #pragma unroll
    for (int nt = 0; nt < 4; ++nt) {
      int j = nt * 16 + l16;
      #pragma unroll
      for (int mt = 0; mt < 2; ++mt) {
        bf16x4 pk;
        #pragma unroll
        for (int r = 0; r < 4; ++r) pk[r] = (bf16_t)acc[mt][nt][r];
        *(bf16x4*)&sm.u.p2.attT[j * NS + swz(j, sb + mt * 16 + q4 * 4)] = pk;
      }
    }
  }
  __syncthreads();
  {
    const int cb = w * 64;
    f32x4 acc[4][4] = {};
    for (int ks = 0; ks < 4; ++ks) {
      const int kb = ks * 32 + q4 * 8;
      bf16x8 afr[4];
      #pragma unroll
      for (int mt = 0; mt < 4; ++mt)
        afr[mt] = ldg_w8(wo + (cb + mt * 16 + l16) * NS + kb);
      #pragma unroll
      for (int nt = 0; nt < 4; ++nt) {
        int jrow = nt * 16 + l16;
        bf16x8 bfr = *(const bf16x8*)&sm.u.p2.attT[jrow * NS + swz(jrow, kb)];
        #pragma unroll
        for (int mt = 0; mt < 4; ++mt)
          acc[mt][nt] = MFMA16(afr[mt], bfr, acc[mt][nt], 0, 0, 0);
      }
    }
    #pragma unroll
    for (int mt = 0; mt < 4; ++mt) {
      #pragma unroll
      for (int r = 0; r < 4; ++r) {
        int c = cb + mt * 16 + q4 * 4 + r;
        float bias = bo[c];
        #pragma unroll
        for (int nt = 0; nt < 4; ++nt) {
          int d = nt * 16 + l16;
          size_t gi = (size_t)(((b * NC + c) * ND + d) * NHW + hw);
          out[gi] = acc[mt][nt][r] + bias + x[gi];
        }
      }
    }
  }
}

extern "C" void kernel_launch(void* const* d_in, const int* in_sizes, int n_in,
                              void* d_out, int out_size, void* d_ws, size_t ws_size,
                              hipStream_t stream) {
  const float* x  = (const float*)d_in[0];
  const float* wk = (const float*)d_in[1];
  const float* bk = (const float*)d_in[2];
  const float* wq = (const float*)d_in[3];
  const float* bq = (const float*)d_in[4];
  const float* wv = (const float*)d_in[5];
  const float* bv = (const float*)d_in[6];
  const float* wo = (const float*)d_in[7];
  const float* bo = (const float*)d_in[8];
  float* out = (float*)d_out;

  // ws: [weights bf16 131072 el | xT 33554432 el | att 16777216 el]
  const size_t need = (size_t)(131072 + 33554432 + 16777216) * 2;
  if (ws_size >= need) {
    bf16_t* wsW = (bf16_t*)d_ws;
    bf16_t* xT  = wsW + 131072;
    bf16_t* att = xT + 33554432;
    transpose_x_w<<<dim3(8224), dim3(256), 0, stream>>>(x, wk, wq, wv, wo, xT, wsW);
    qkv_attn3<<<dim3(2048), dim3(256), 0, stream>>>(xT, wsW, bk, bq, bv, att);
    out_proj4<<<dim3(4096), dim3(256), 0, stream>>>(att, wsW + 98304, bo, x, out);
  } else {
    attn_fused<<<dim3(2048), dim3(256), 0, stream>>>(x, wk, bk, wq, bq, wv, bv, wo, bo, out);
  }
}